// Round 8
// baseline (289.320 us; speedup 1.0000x reference)
//
#include <hip/hip_runtime.h>
#include <math.h>

#define F_IN 500
#define F_HID 128
#define F_OUT 47
#define NGRP 8

typedef __attribute__((ext_vector_type(8))) short short8;
typedef __attribute__((ext_vector_type(4))) float f32x4;

__device__ inline unsigned pack_bf16x2(float a, float b) {
    unsigned ua = __float_as_uint(a), ub = __float_as_uint(b);
    ua = (ua + 0x7FFFu + ((ua >> 16) & 1u)) >> 16;
    ub = (ub + 0x7FFFu + ((ub >> 16) & 1u)) >> 16;
    return ua | (ub << 16);
}
__device__ inline unsigned short pack_bf16(float a) {
    unsigned u = __float_as_uint(a);
    return (unsigned short)((u + 0x7FFFu + ((u >> 16) & 1u)) >> 16);
}

// ---------------- degree / norm / CSR build ----------------
__global__ void k_zero(int* __restrict__ p, int n) {
    int i = blockIdx.x * 256 + threadIdx.x;
    if (i < n) p[i] = 0;
}

// XCD-partitioned: group g = blockIdx&7 handles dst in [g*n/8,(g+1)*n/8)
__global__ void k_deg_count(const int* __restrict__ ei, int* __restrict__ ecnt,
                            int E, int n) {
    int g = blockIdx.x & (NGRP - 1);
    int bi = blockIdx.x >> 3;
    int nbg = gridDim.x >> 3;
    int lo = (int)((long)g * n / NGRP), hi = (int)((long)(g + 1) * n / NGRP);
    for (int e = bi * 256 + threadIdx.x; e < E; e += nbg * 256) {
        int d = ei[E + e];
        if (d >= lo && d < hi) atomicAdd(&ecnt[d], 1);
    }
}

// ---------------- 3-phase device-wide exclusive scan (+ dinv fused) ----------------
__global__ __launch_bounds__(1024) void k_scanA(const int* __restrict__ ecnt,
                                                int* __restrict__ rowptr,
                                                int* __restrict__ bsum,
                                                float* __restrict__ dinv, int n) {
    __shared__ int tmp[1024];
    int t = threadIdx.x;
    int gid = blockIdx.x * 1024 + t;
    int v = (gid < n) ? ecnt[gid] : 0;
    if (gid < n) dinv[gid] = rsqrtf((float)(v + 1));  // +1 self-loop
    tmp[t] = v;
    __syncthreads();
    for (int off = 1; off < 1024; off <<= 1) {
        int u = (t >= off) ? tmp[t - off] : 0;
        __syncthreads();
        tmp[t] += u;
        __syncthreads();
    }
    if (gid < n) rowptr[gid] = tmp[t] - v;
    if (t == 1023) bsum[blockIdx.x] = tmp[1023];
}

__global__ void k_scanB(const int* __restrict__ bsum, int* __restrict__ boffs, int nb) {
    int t = threadIdx.x;
    int v = (t < nb) ? bsum[t] : 0;
    int inc = v;
#pragma unroll
    for (int off = 1; off < 64; off <<= 1) {
        int u = __shfl_up(inc, off);
        if (t >= off) inc += u;
    }
    if (t < nb) boffs[t] = inc - v;
    if (t == nb - 1) boffs[nb] = inc;
}

__global__ __launch_bounds__(1024) void k_scanC(int* __restrict__ rowptr,
                                                int* __restrict__ cur,
                                                const int* __restrict__ boffs,
                                                int n, int nb) {
    int gid = blockIdx.x * 1024 + threadIdx.x;
    if (gid < n) {
        int v = rowptr[gid] + boffs[blockIdx.x];
        rowptr[gid] = v;
        cur[gid] = v;
    } else if (gid == n) {
        rowptr[n] = boffs[nb];
    }
}

// XCD-partitioned CSR fill
__global__ void k_fill(const int* __restrict__ ei, int* __restrict__ cur,
                       int* __restrict__ csr, int E, int n) {
    int g = blockIdx.x & (NGRP - 1);
    int bi = blockIdx.x >> 3;
    int nbg = gridDim.x >> 3;
    int lo = (int)((long)g * n / NGRP), hi = (int)((long)(g + 1) * n / NGRP);
    for (int e = bi * 256 + threadIdx.x; e < E; e += nbg * 256) {
        int d = ei[E + e];
        if (d >= lo && d < hi) {
            int pos = atomicAdd(&cur[d], 1);
            csr[pos] = ei[e];  // src
        }
    }
}

// ---------------- W1 -> bf16, transposed [128 cols][512 k] ----------------
__global__ void k_w1cvt(const float* __restrict__ W1, unsigned short* __restrict__ Btg) {
    int id = blockIdx.x * 256 + threadIdx.x;  // 65536 total
    int kk = id >> 7, c = id & 127;
    float v = (kk < F_IN) ? W1[kk * F_HID + c] : 0.f;
    Btg[c * 512 + kk] = pack_bf16(v);
}

// ---------------- GEMM1 (bf16 MFMA): hs16 = bf16((x @ W1) * dinv) ----------------
#define BM 32
#define BK 64
__global__ __launch_bounds__(256, 4) void k_gemm1_mfma(const float* __restrict__ x,
                                                       const unsigned short* __restrict__ Btg,
                                                       const float* __restrict__ dinv,
                                                       unsigned short* __restrict__ hs16, int n) {
    __shared__ unsigned short As[BM * BK];     // 4 KB, XOR-swizzled
    __shared__ unsigned short Bs[F_HID * BK];  // 16 KB, XOR-swizzled
    int t = threadIdx.x;
    int row0 = blockIdx.x * BM;
    int w = t >> 6, l = t & 63;

    int ar = t >> 3, acg = t & 7;
    int agrow = row0 + ar;
    int abyte = ar * 128 + ((acg * 16) ^ ((ar & 7) << 4));

    f32x4 acc[2][2] = {};

    float4 a0, a1;
    uint4 bq0, bq1, bq2, bq3;

#define LOAD_A(c, f0, f1)                                              \
    {                                                                  \
        int kbase = (c) * BK + acg * 8;                                \
        f0 = make_float4(0.f, 0.f, 0.f, 0.f);                          \
        f1 = make_float4(0.f, 0.f, 0.f, 0.f);                         \
        if (agrow < n) {                                               \
            const float* p = x + (long)agrow * F_IN + kbase;           \
            if (kbase + 4 <= F_IN) f0 = *(const float4*)p;             \
            if (kbase + 8 <= F_IN) f1 = *(const float4*)(p + 4);       \
        }                                                              \
    }
#define LOAD_B1(c, dst, uu)                                            \
    {                                                                  \
        int u = t + (uu) * 256;                                        \
        int r = u >> 3, cg = u & 7;                                    \
        dst = *(const uint4*)(Btg + r * 512 + (c) * BK + cg * 8);      \
    }

    LOAD_A(0, a0, a1);
    LOAD_B1(0, bq0, 0); LOAD_B1(0, bq1, 1); LOAD_B1(0, bq2, 2); LOAD_B1(0, bq3, 3);

    for (int c = 0; c < 8; ++c) {
        uint4 pk;
        pk.x = pack_bf16x2(a0.x, a0.y);
        pk.y = pack_bf16x2(a0.z, a0.w);
        pk.z = pack_bf16x2(a1.x, a1.y);
        pk.w = pack_bf16x2(a1.z, a1.w);
        *(uint4*)((char*)As + abyte) = pk;
#pragma unroll
        for (int uu = 0; uu < 4; ++uu) {
            int u = t + uu * 256;
            int r = u >> 3, cg = u & 7;
            int byte = r * 128 + ((cg * 16) ^ ((r & 7) << 4));
            uint4 v = (uu == 0) ? bq0 : (uu == 1) ? bq1 : (uu == 2) ? bq2 : bq3;
            *(uint4*)((char*)Bs + byte) = v;
        }
        __syncthreads();

        float4 na0 = make_float4(0.f, 0.f, 0.f, 0.f), na1 = na0;
        uint4 nb0 = {}, nb1 = {}, nb2 = {}, nb3 = {};
        if (c < 7) {
            LOAD_A(c + 1, na0, na1);
            LOAD_B1(c + 1, nb0, 0); LOAD_B1(c + 1, nb1, 1);
            LOAD_B1(c + 1, nb2, 2); LOAD_B1(c + 1, nb3, 3);
        }

        int lr = l & 15;
        int lkb = (l >> 4) * 16;
        short8 af[2][2], bf[2][2];
#pragma unroll
        for (int mi = 0; mi < 2; ++mi)
#pragma unroll
            for (int ks = 0; ks < 2; ++ks) {
                int r = mi * 16 + lr;
                int byte = r * 128 + (((ks * 64) + lkb) ^ ((r & 7) << 4));
                af[mi][ks] = *(short8*)((char*)As + byte);
            }
#pragma unroll
        for (int ni = 0; ni < 2; ++ni)
#pragma unroll
            for (int ks = 0; ks < 2; ++ks) {
                int r = w * 32 + ni * 16 + lr;
                int byte = r * 128 + (((ks * 64) + lkb) ^ ((r & 7) << 4));
                bf[ni][ks] = *(short8*)((char*)Bs + byte);
            }
#pragma unroll
        for (int mi = 0; mi < 2; ++mi)
#pragma unroll
            for (int ni = 0; ni < 2; ++ni)
#pragma unroll
                for (int ks = 0; ks < 2; ++ks)
                    acc[mi][ni] = __builtin_amdgcn_mfma_f32_16x16x32_bf16(
                        af[mi][ks], bf[ni][ks], acc[mi][ni], 0, 0, 0);
        __syncthreads();

        a0 = na0; a1 = na1;
        bq0 = nb0; bq1 = nb1; bq2 = nb2; bq3 = nb3;
    }

#pragma unroll
    for (int mi = 0; mi < 2; ++mi) {
        int rb = row0 + mi * 16 + (l >> 4) * 4;
        float dv[4];
#pragma unroll
        for (int reg = 0; reg < 4; ++reg)
            dv[reg] = (rb + reg < n) ? dinv[rb + reg] : 0.f;
#pragma unroll
        for (int ni = 0; ni < 2; ++ni) {
            int col = w * 32 + ni * 16 + (l & 15);
#pragma unroll
            for (int reg = 0; reg < 4; ++reg) {
                int row = rb + reg;
                if (row < n) hs16[(long)row * F_HID + col] = pack_bf16(acc[mi][ni][reg] * dv[reg]);
            }
        }
    }
#undef LOAD_A
#undef LOAD_B1
}

// ---------------- fused middle: gather1 + relu/bias + GEMM2 -> hs2 (bf16, 64-col pad) ----
// 512 thr = 8 waves; wave w owns node blockIdx*8+w. Phase 1: 64-lane gather of
// bf16 rows (lane l -> cols 2l,2l+1), relu(dinv*agg+b1) -> LDS. Phase 2: lane<47
// dots the LDS row with LDS-resident W2; writes bf16 padded row.
#define MID_NODES 8
__global__ __launch_bounds__(512) void k_mid(const unsigned short* __restrict__ hs16,
                                             const int* __restrict__ rowptr,
                                             const int* __restrict__ csr,
                                             const float* __restrict__ dinv,
                                             const float* __restrict__ b1,
                                             const float* __restrict__ W2,
                                             unsigned short* __restrict__ hs2, int n) {
    __shared__ float w2s[F_HID * F_OUT];      // 24 KB
    __shared__ float rs[MID_NODES][F_HID];    // 4 KB
    for (int i = threadIdx.x; i < F_HID * F_OUT; i += 512) w2s[i] = W2[i];
    int w = threadIdx.x >> 6, l = threadIdx.x & 63;
    int node = blockIdx.x * MID_NODES + w;
    if (node < n) {
        int c0 = 2 * l;
        float v0, v1;
        {
            unsigned u = *(const unsigned*)(hs16 + (long)node * F_HID + c0);  // self
            v0 = __uint_as_float(u << 16);
            v1 = __uint_as_float(u & 0xFFFF0000u);
        }
        int lo = rowptr[node], hi = rowptr[node + 1];
        for (int e = lo; e < hi; ++e) {
            int s = csr[e];
            unsigned u = *(const unsigned*)(hs16 + (long)s * F_HID + c0);
            v0 += __uint_as_float(u << 16);
            v1 += __uint_as_float(u & 0xFFFF0000u);
        }
        float dv = dinv[node];
        rs[w][c0]     = fmaxf(dv * v0 + b1[c0], 0.f);
        rs[w][c0 + 1] = fmaxf(dv * v1 + b1[c0 + 1], 0.f);
    }
    __syncthreads();
    if (node < n) {
        float v = 0.f;
        if (l < F_OUT) {
            float s = 0.f;
#pragma unroll 8
            for (int k = 0; k < F_HID; ++k) s += rs[w][k] * w2s[k * F_OUT + l];
            v = s * dinv[node];
        }
        hs2[(long)node * 64 + l] = pack_bf16(v);  // pad cols 47..63 = 0
    }
}

// ---------------- gather layer 2 + bias + log_softmax ----------------
__global__ __launch_bounds__(256) void k_out(const unsigned short* __restrict__ hs2,
                                             const int* __restrict__ rowptr,
                                             const int* __restrict__ csr,
                                             const float* __restrict__ dinv,
                                             const float* __restrict__ b2,
                                             float* __restrict__ out, int n) {
    int tid = blockIdx.x * 256 + threadIdx.x;
    int node = tid >> 5;
    if (node >= n) return;
    int q = tid & 31;
    int c0 = 2 * q, c1 = 2 * q + 1;
    float v0, v1;
    {
        unsigned u = *(const unsigned*)(hs2 + (long)node * 64 + c0);  // self
        v0 = __uint_as_float(u << 16);
        v1 = __uint_as_float(u & 0xFFFF0000u);
    }
    int lo = rowptr[node], hi = rowptr[node + 1];
    for (int e = lo; e < hi; ++e) {
        int s = csr[e];
        unsigned u = *(const unsigned*)(hs2 + (long)s * 64 + c0);
        v0 += __uint_as_float(u << 16);
        v1 += __uint_as_float(u & 0xFFFF0000u);
    }
    float dv = dinv[node];
    float z0 = (c0 < F_OUT) ? v0 * dv + b2[c0] : -INFINITY;
    float z1 = (c1 < F_OUT) ? v1 * dv + b2[c1] : -INFINITY;
    float m = fmaxf(z0, z1);
#pragma unroll
    for (int o = 16; o; o >>= 1) m = fmaxf(m, __shfl_xor(m, o));
    float sum = ((c0 < F_OUT) ? __expf(z0 - m) : 0.f) + ((c1 < F_OUT) ? __expf(z1 - m) : 0.f);
#pragma unroll
    for (int o = 16; o; o >>= 1) sum += __shfl_xor(sum, o);
    float ls = logf(sum) + m;
    if (c0 < F_OUT) out[(long)node * F_OUT + c0] = z0 - ls;
    if (c1 < F_OUT) out[(long)node * F_OUT + c1] = z1 - ls;
}

extern "C" void kernel_launch(void* const* d_in, const int* in_sizes, int n_in,
                              void* d_out, int out_size, void* d_ws, size_t ws_size,
                              hipStream_t stream) {
    const float* x  = (const float*)d_in[0];
    const float* W1 = (const float*)d_in[1];
    const float* b1 = (const float*)d_in[2];
    const float* W2 = (const float*)d_in[3];
    const float* b2 = (const float*)d_in[4];
    const int*   ei = (const int*)d_in[5];

    int n = in_sizes[0] / F_IN;      // 50000
    int E = in_sizes[5] / 2;         // 800000
    float* out = (float*)d_out;

    // workspace layout
    char* ws = (char*)d_ws;
    float* dinv   = (float*)(ws + 0);          // 200 KB
    int*   ecnt   = (int*)  (ws + 200704);
    int*   rowptr = (int*)  (ws + 401408);     // n+1 ints
    int*   cur    = (int*)  (ws + 602112);     // dead after k_fill; Btg aliases it
    unsigned short* Btg = (unsigned short*)(ws + 602112);  // 128 KB (ends 733184)
    int*   bsum   = (int*)  (ws + 733184);
    int*   boffs  = (int*)  (ws + 737280);
    int*   csr    = (int*)  (ws + 802816);     // 3.2 MB
    unsigned short* hs16  = (unsigned short*)(ws + 4003840);   // 12.8 MB
    unsigned short* hs2   = (unsigned short*)(ws + 16804864);  // 6.4 MB

    int nb = (n + 255) / 256;
    int sb = (n + 1023) / 1024;
    k_zero<<<nb, 256, 0, stream>>>(ecnt, n);
    k_deg_count<<<1024, 256, 0, stream>>>(ei, ecnt, E, n);
    k_scanA<<<sb, 1024, 0, stream>>>(ecnt, rowptr, bsum, dinv, n);
    k_scanB<<<1, 64, 0, stream>>>(bsum, boffs, sb);
    k_scanC<<<sb, 1024, 0, stream>>>(rowptr, cur, boffs, n, sb);
    k_fill<<<1024, 256, 0, stream>>>(ei, cur, csr, E, n);
    k_w1cvt<<<256, 256, 0, stream>>>(W1, Btg);

    k_gemm1_mfma<<<(n + BM - 1) / BM, 256, 0, stream>>>(x, Btg, dinv, hs16, n);
    k_mid<<<(n + MID_NODES - 1) / MID_NODES, 512, 0, stream>>>(hs16, rowptr, csr, dinv, b1, W2, hs2, n);
    k_out<<<(n * 32 + 255) / 256, 256, 0, stream>>>(hs2, rowptr, csr, dinv, b2, out, n);
}

// Round 9
// 236.102 us; speedup vs baseline: 1.2254x; 1.2254x over previous
//
#include <hip/hip_runtime.h>
#include <math.h>

#define F_IN 500
#define F_HID 128
#define F_OUT 47
#define NGRP 8

typedef __attribute__((ext_vector_type(8))) short short8;
typedef __attribute__((ext_vector_type(4))) float f32x4;

__device__ inline unsigned pack_bf16x2(float a, float b) {
    unsigned ua = __float_as_uint(a), ub = __float_as_uint(b);
    ua = (ua + 0x7FFFu + ((ua >> 16) & 1u)) >> 16;
    ub = (ub + 0x7FFFu + ((ub >> 16) & 1u)) >> 16;
    return ua | (ub << 16);
}
__device__ inline unsigned short pack_bf16(float a) {
    unsigned u = __float_as_uint(a);
    return (unsigned short)((u + 0x7FFFu + ((u >> 16) & 1u)) >> 16);
}

// ---------------- degree / norm / CSR build ----------------
__global__ void k_zero(int* __restrict__ p, int n) {
    int i = blockIdx.x * 256 + threadIdx.x;
    if (i < n) p[i] = 0;
}

// XCD-partitioned: group g = blockIdx&7 handles dst in [g*n/8,(g+1)*n/8)
__global__ void k_deg_count(const int* __restrict__ ei, int* __restrict__ ecnt,
                            int E, int n) {
    int g = blockIdx.x & (NGRP - 1);
    int bi = blockIdx.x >> 3;
    int nbg = gridDim.x >> 3;
    int lo = (int)((long)g * n / NGRP), hi = (int)((long)(g + 1) * n / NGRP);
    for (int e = bi * 256 + threadIdx.x; e < E; e += nbg * 256) {
        int d = ei[E + e];
        if (d >= lo && d < hi) atomicAdd(&ecnt[d], 1);
    }
}

// ---------------- 3-phase device-wide exclusive scan (+ dinv fused) ----------------
__global__ __launch_bounds__(1024) void k_scanA(const int* __restrict__ ecnt,
                                                int* __restrict__ rowptr,
                                                int* __restrict__ bsum,
                                                float* __restrict__ dinv, int n) {
    __shared__ int tmp[1024];
    int t = threadIdx.x;
    int gid = blockIdx.x * 1024 + t;
    int v = (gid < n) ? ecnt[gid] : 0;
    if (gid < n) dinv[gid] = rsqrtf((float)(v + 1));  // +1 self-loop
    tmp[t] = v;
    __syncthreads();
    for (int off = 1; off < 1024; off <<= 1) {
        int u = (t >= off) ? tmp[t - off] : 0;
        __syncthreads();
        tmp[t] += u;
        __syncthreads();
    }
    if (gid < n) rowptr[gid] = tmp[t] - v;
    if (t == 1023) bsum[blockIdx.x] = tmp[1023];
}

__global__ void k_scanB(const int* __restrict__ bsum, int* __restrict__ boffs, int nb) {
    int t = threadIdx.x;
    int v = (t < nb) ? bsum[t] : 0;
    int inc = v;
#pragma unroll
    for (int off = 1; off < 64; off <<= 1) {
        int u = __shfl_up(inc, off);
        if (t >= off) inc += u;
    }
    if (t < nb) boffs[t] = inc - v;
    if (t == nb - 1) boffs[nb] = inc;
}

__global__ __launch_bounds__(1024) void k_scanC(int* __restrict__ rowptr,
                                                int* __restrict__ cur,
                                                const int* __restrict__ boffs,
                                                int n, int nb) {
    int gid = blockIdx.x * 1024 + threadIdx.x;
    if (gid < n) {
        int v = rowptr[gid] + boffs[blockIdx.x];
        rowptr[gid] = v;
        cur[gid] = v;
    } else if (gid == n) {
        rowptr[n] = boffs[nb];
    }
}

// XCD-partitioned CSR fill
__global__ void k_fill(const int* __restrict__ ei, int* __restrict__ cur,
                       int* __restrict__ csr, int E, int n) {
    int g = blockIdx.x & (NGRP - 1);
    int bi = blockIdx.x >> 3;
    int nbg = gridDim.x >> 3;
    int lo = (int)((long)g * n / NGRP), hi = (int)((long)(g + 1) * n / NGRP);
    for (int e = bi * 256 + threadIdx.x; e < E; e += nbg * 256) {
        int d = ei[E + e];
        if (d >= lo && d < hi) {
            int pos = atomicAdd(&cur[d], 1);
            csr[pos] = ei[e];  // src
        }
    }
}

// ---------------- weight converts: W1 -> Btg[128 cols][512 k]; W2 -> Wt2[64 cols][128 k] ----
__global__ void k_wcvt(const float* __restrict__ W1, const float* __restrict__ W2,
                       unsigned short* __restrict__ Btg, unsigned short* __restrict__ Wt2) {
    int b = blockIdx.x;
    if (b < 256) {
        int id = b * 256 + threadIdx.x;   // 65536
        int kk = id >> 7, c = id & 127;
        float v = (kk < F_IN) ? W1[kk * F_HID + c] : 0.f;
        Btg[c * 512 + kk] = pack_bf16(v);
    } else {
        int id = (b - 256) * 256 + threadIdx.x;  // 8192 (32 blocks)
        int c = id >> 7, kk = id & 127;          // Wt2[col][k], cols 47..63 zero
        float v = (c < F_OUT) ? W2[kk * F_OUT + c] : 0.f;
        Wt2[c * 128 + kk] = pack_bf16(v);
    }
}

// ---------------- GEMM1 (bf16 MFMA): hs16 = bf16((x @ W1) * dinv) ----------------
#define BM 32
#define BK 64
__global__ __launch_bounds__(256, 4) void k_gemm1_mfma(const float* __restrict__ x,
                                                       const unsigned short* __restrict__ Btg,
                                                       const float* __restrict__ dinv,
                                                       unsigned short* __restrict__ hs16, int n) {
    __shared__ unsigned short As[BM * BK];     // 4 KB, XOR-swizzled
    __shared__ unsigned short Bs[F_HID * BK];  // 16 KB, XOR-swizzled
    int t = threadIdx.x;
    int row0 = blockIdx.x * BM;
    int w = t >> 6, l = t & 63;

    int ar = t >> 3, acg = t & 7;
    int agrow = row0 + ar;
    int abyte = ar * 128 + ((acg * 16) ^ ((ar & 7) << 4));

    f32x4 acc[2][2] = {};

    float4 a0, a1;
    uint4 bq0, bq1, bq2, bq3;

#define LOAD_A(c, f0, f1)                                              \
    {                                                                  \
        int kbase = (c) * BK + acg * 8;                                \
        f0 = make_float4(0.f, 0.f, 0.f, 0.f);                          \
        f1 = make_float4(0.f, 0.f, 0.f, 0.f);                         \
        if (agrow < n) {                                               \
            const float* p = x + (long)agrow * F_IN + kbase;           \
            if (kbase + 4 <= F_IN) f0 = *(const float4*)p;             \
            if (kbase + 8 <= F_IN) f1 = *(const float4*)(p + 4);       \
        }                                                              \
    }
#define LOAD_B1(c, dst, uu)                                            \
    {                                                                  \
        int u = t + (uu) * 256;                                        \
        int r = u >> 3, cg = u & 7;                                    \
        dst = *(const uint4*)(Btg + r * 512 + (c) * BK + cg * 8);      \
    }

    LOAD_A(0, a0, a1);
    LOAD_B1(0, bq0, 0); LOAD_B1(0, bq1, 1); LOAD_B1(0, bq2, 2); LOAD_B1(0, bq3, 3);

    for (int c = 0; c < 8; ++c) {
        uint4 pk;
        pk.x = pack_bf16x2(a0.x, a0.y);
        pk.y = pack_bf16x2(a0.z, a0.w);
        pk.z = pack_bf16x2(a1.x, a1.y);
        pk.w = pack_bf16x2(a1.z, a1.w);
        *(uint4*)((char*)As + abyte) = pk;
#pragma unroll
        for (int uu = 0; uu < 4; ++uu) {
            int u = t + uu * 256;
            int r = u >> 3, cg = u & 7;
            int byte = r * 128 + ((cg * 16) ^ ((r & 7) << 4));
            uint4 v = (uu == 0) ? bq0 : (uu == 1) ? bq1 : (uu == 2) ? bq2 : bq3;
            *(uint4*)((char*)Bs + byte) = v;
        }
        __syncthreads();

        float4 na0 = make_float4(0.f, 0.f, 0.f, 0.f), na1 = na0;
        uint4 nb0 = {}, nb1 = {}, nb2 = {}, nb3 = {};
        if (c < 7) {
            LOAD_A(c + 1, na0, na1);
            LOAD_B1(c + 1, nb0, 0); LOAD_B1(c + 1, nb1, 1);
            LOAD_B1(c + 1, nb2, 2); LOAD_B1(c + 1, nb3, 3);
        }

        int lr = l & 15;
        int lkb = (l >> 4) * 16;
        short8 af[2][2], bf[2][2];
#pragma unroll
        for (int mi = 0; mi < 2; ++mi)
#pragma unroll
            for (int ks = 0; ks < 2; ++ks) {
                int r = mi * 16 + lr;
                int byte = r * 128 + (((ks * 64) + lkb) ^ ((r & 7) << 4));
                af[mi][ks] = *(short8*)((char*)As + byte);
            }
#pragma unroll
        for (int ni = 0; ni < 2; ++ni)
#pragma unroll
            for (int ks = 0; ks < 2; ++ks) {
                int r = w * 32 + ni * 16 + lr;
                int byte = r * 128 + (((ks * 64) + lkb) ^ ((r & 7) << 4));
                bf[ni][ks] = *(short8*)((char*)Bs + byte);
            }
#pragma unroll
        for (int mi = 0; mi < 2; ++mi)
#pragma unroll
            for (int ni = 0; ni < 2; ++ni)
#pragma unroll
                for (int ks = 0; ks < 2; ++ks)
                    acc[mi][ni] = __builtin_amdgcn_mfma_f32_16x16x32_bf16(
                        af[mi][ks], bf[ni][ks], acc[mi][ni], 0, 0, 0);
        __syncthreads();

        a0 = na0; a1 = na1;
        bq0 = nb0; bq1 = nb1; bq2 = nb2; bq3 = nb3;
    }

#pragma unroll
    for (int mi = 0; mi < 2; ++mi) {
        int rb = row0 + mi * 16 + (l >> 4) * 4;
        float dv[4];
#pragma unroll
        for (int reg = 0; reg < 4; ++reg)
            dv[reg] = (rb + reg < n) ? dinv[rb + reg] : 0.f;
#pragma unroll
        for (int ni = 0; ni < 2; ++ni) {
            int col = w * 32 + ni * 16 + (l & 15);
#pragma unroll
            for (int reg = 0; reg < 4; ++reg) {
                int row = rb + reg;
                if (row < n) hs16[(long)row * F_HID + col] = pack_bf16(acc[mi][ni][reg] * dv[reg]);
            }
        }
    }
#undef LOAD_A
#undef LOAD_B1
}

// ---------------- gather layer 1: h1 = bf16(relu(dinv*(hs16[self]+sum hs16[src]) + b1)) ----
// half-wave (32 lanes) per node; lane q holds 4 bf16 cols (uint2), fp32 accum
__global__ __launch_bounds__(256) void k_gather1(const unsigned short* __restrict__ hs16,
                                                 const int* __restrict__ rowptr,
                                                 const int* __restrict__ csr,
                                                 const float* __restrict__ dinv,
                                                 const float* __restrict__ b1,
                                                 unsigned short* __restrict__ h1, int n) {
    int tid = blockIdx.x * 256 + threadIdx.x;
    int node = tid >> 5;
    if (node >= n) return;
    int q = tid & 31;
    float4 v;
    {
        uint2 u = *(const uint2*)(hs16 + (long)node * F_HID + q * 4);  // self
        v.x = __uint_as_float(u.x << 16);
        v.y = __uint_as_float(u.x & 0xFFFF0000u);
        v.z = __uint_as_float(u.y << 16);
        v.w = __uint_as_float(u.y & 0xFFFF0000u);
    }
    int lo = rowptr[node], hi = rowptr[node + 1];
    for (int e = lo; e < hi; ++e) {
        int s = csr[e];
        uint2 u = *(const uint2*)(hs16 + (long)s * F_HID + q * 4);
        v.x += __uint_as_float(u.x << 16);
        v.y += __uint_as_float(u.x & 0xFFFF0000u);
        v.z += __uint_as_float(u.y << 16);
        v.w += __uint_as_float(u.y & 0xFFFF0000u);
    }
    float dv = dinv[node];
    float4 bb = *(const float4*)&b1[q * 4];
    float r0 = fmaxf(dv * v.x + bb.x, 0.f);
    float r1 = fmaxf(dv * v.y + bb.y, 0.f);
    float r2 = fmaxf(dv * v.z + bb.z, 0.f);
    float r3 = fmaxf(dv * v.w + bb.w, 0.f);
    uint2 o;
    o.x = pack_bf16x2(r0, r1);
    o.y = pack_bf16x2(r2, r3);
    *(uint2*)(h1 + (long)node * F_HID + q * 4) = o;
}

// ---------------- GEMM2 (bf16 MFMA, no LDS): hs2 = bf16((h1 @ W2) * dinv), 64-col pad ----
// 4 waves/block; wave w: rows row0+(w&1)*16.., cols (w>>1)*32.. (2 frags of 16)
__global__ __launch_bounds__(256, 4) void k_gemm2_mfma(const unsigned short* __restrict__ h1,
                                                       const unsigned short* __restrict__ Wt2,
                                                       const float* __restrict__ dinv,
                                                       unsigned short* __restrict__ hs2, int n) {
    int t = threadIdx.x, w = t >> 6, l = t & 63;
    int row0 = blockIdx.x * 32 + (w & 1) * 16;
    int col0 = (w >> 1) * 32;
    int lr = l & 15, lk = (l >> 4) * 8;

    short8 bf[2][4];
#pragma unroll
    for (int nf = 0; nf < 2; ++nf)
#pragma unroll
        for (int ks = 0; ks < 4; ++ks)
            bf[nf][ks] = *(const short8*)(Wt2 + (col0 + nf * 16 + lr) * 128 + ks * 32 + lk);

    int arow = row0 + lr;
    const short8 z8 = {};
    f32x4 acc[2] = {};
#pragma unroll
    for (int ks = 0; ks < 4; ++ks) {
        short8 af = (arow < n) ? *(const short8*)(h1 + (long)arow * F_HID + ks * 32 + lk) : z8;
#pragma unroll
        for (int nf = 0; nf < 2; ++nf)
            acc[nf] = __builtin_amdgcn_mfma_f32_16x16x32_bf16(af, bf[nf][ks], acc[nf], 0, 0, 0);
    }

    int rb = row0 + (l >> 4) * 4;
#pragma unroll
    for (int nf = 0; nf < 2; ++nf) {
        int col = col0 + nf * 16 + lr;
#pragma unroll
        for (int reg = 0; reg < 4; ++reg) {
            int row = rb + reg;
            if (row < n) hs2[(long)row * 64 + col] = pack_bf16(acc[nf][reg] * dinv[row]);
        }
    }
}

// ---------------- gather layer 2 + bias + log_softmax ----------------
__global__ __launch_bounds__(256) void k_out(const unsigned short* __restrict__ hs2,
                                             const int* __restrict__ rowptr,
                                             const int* __restrict__ csr,
                                             const float* __restrict__ dinv,
                                             const float* __restrict__ b2,
                                             float* __restrict__ out, int n) {
    int tid = blockIdx.x * 256 + threadIdx.x;
    int node = tid >> 5;
    if (node >= n) return;
    int q = tid & 31;
    int c0 = 2 * q, c1 = 2 * q + 1;
    float v0, v1;
    {
        unsigned u = *(const unsigned*)(hs2 + (long)node * 64 + c0);  // self
        v0 = __uint_as_float(u << 16);
        v1 = __uint_as_float(u & 0xFFFF0000u);
    }
    int lo = rowptr[node], hi = rowptr[node + 1];
    for (int e = lo; e < hi; ++e) {
        int s = csr[e];
        unsigned u = *(const unsigned*)(hs2 + (long)s * 64 + c0);
        v0 += __uint_as_float(u << 16);
        v1 += __uint_as_float(u & 0xFFFF0000u);
    }
    float dv = dinv[node];
    float z0 = (c0 < F_OUT) ? v0 * dv + b2[c0] : -INFINITY;
    float z1 = (c1 < F_OUT) ? v1 * dv + b2[c1] : -INFINITY;
    float m = fmaxf(z0, z1);
#pragma unroll
    for (int o = 16; o; o >>= 1) m = fmaxf(m, __shfl_xor(m, o));
    float sum = ((c0 < F_OUT) ? __expf(z0 - m) : 0.f) + ((c1 < F_OUT) ? __expf(z1 - m) : 0.f);
#pragma unroll
    for (int o = 16; o; o >>= 1) sum += __shfl_xor(sum, o);
    float ls = logf(sum) + m;
    if (c0 < F_OUT) out[(long)node * F_OUT + c0] = z0 - ls;
    if (c1 < F_OUT) out[(long)node * F_OUT + c1] = z1 - ls;
}

extern "C" void kernel_launch(void* const* d_in, const int* in_sizes, int n_in,
                              void* d_out, int out_size, void* d_ws, size_t ws_size,
                              hipStream_t stream) {
    const float* x  = (const float*)d_in[0];
    const float* W1 = (const float*)d_in[1];
    const float* b1 = (const float*)d_in[2];
    const float* W2 = (const float*)d_in[3];
    const float* b2 = (const float*)d_in[4];
    const int*   ei = (const int*)d_in[5];

    int n = in_sizes[0] / F_IN;      // 50000
    int E = in_sizes[5] / 2;         // 800000
    float* out = (float*)d_out;

    // workspace layout
    char* ws = (char*)d_ws;
    float* dinv   = (float*)(ws + 0);          // 200 KB
    int*   ecnt   = (int*)  (ws + 200704);
    int*   rowptr = (int*)  (ws + 401408);     // n+1 ints
    int*   cur    = (int*)  (ws + 602112);     // dead after k_fill; Btg aliases it
    unsigned short* Btg = (unsigned short*)(ws + 602112);  // 128 KB (ends 733184)
    int*   bsum   = (int*)  (ws + 733184);
    int*   boffs  = (int*)  (ws + 737280);
    unsigned short* Wt2 = (unsigned short*)(ws + 741376);  // 16 KB (ends 757760)
    int*   csr    = (int*)  (ws + 802816);     // 3.2 MB
    unsigned short* hs16  = (unsigned short*)(ws + 4003840);   // 12.8 MB
    unsigned short* hs2   = (unsigned short*)(ws + 16804864);  // 6.4 MB
    unsigned short* h1    = (unsigned short*)(ws + 29603840);  // 12.8 MB (bf16 now)

    int nb = (n + 255) / 256;
    int sb = (n + 1023) / 1024;
    k_zero<<<nb, 256, 0, stream>>>(ecnt, n);
    k_deg_count<<<1024, 256, 0, stream>>>(ei, ecnt, E, n);
    k_scanA<<<sb, 1024, 0, stream>>>(ecnt, rowptr, bsum, dinv, n);
    k_scanB<<<1, 64, 0, stream>>>(bsum, boffs, sb);
    k_scanC<<<sb, 1024, 0, stream>>>(rowptr, cur, boffs, n, sb);
    k_fill<<<1024, 256, 0, stream>>>(ei, cur, csr, E, n);
    k_wcvt<<<288, 256, 0, stream>>>(W1, W2, Btg, Wt2);

    k_gemm1_mfma<<<(n + BM - 1) / BM, 256, 0, stream>>>(x, Btg, dinv, hs16, n);
    k_gather1<<<(n * 32 + 255) / 256, 256, 0, stream>>>(hs16, rowptr, csr, dinv, b1, h1, n);
    k_gemm2_mfma<<<(n + 31) / 32, 256, 0, stream>>>(h1, Wt2, dinv, hs2, n);
    k_out<<<(n * 32 + 255) / 256, 256, 0, stream>>>(hs2, rowptr, csr, dinv, b2, out, n);
}

// Round 10
// 234.519 us; speedup vs baseline: 1.2337x; 1.0067x over previous
//
#include <hip/hip_runtime.h>
#include <math.h>

#define F_IN 500
#define F_HID 128
#define F_OUT 47
#define NGRP 8

typedef __attribute__((ext_vector_type(8))) short short8;
typedef __attribute__((ext_vector_type(4))) float f32x4;

__device__ inline unsigned pack_bf16x2(float a, float b) {
    unsigned ua = __float_as_uint(a), ub = __float_as_uint(b);
    ua = (ua + 0x7FFFu + ((ua >> 16) & 1u)) >> 16;
    ub = (ub + 0x7FFFu + ((ub >> 16) & 1u)) >> 16;
    return ua | (ub << 16);
}
__device__ inline unsigned short pack_bf16(float a) {
    unsigned u = __float_as_uint(a);
    return (unsigned short)((u + 0x7FFFu + ((u >> 16) & 1u)) >> 16);
}

// async global->LDS, 16B per lane, dest = wave-uniform base + lane*16
__device__ __forceinline__ void gload_lds16(const void* g, void* l) {
    __builtin_amdgcn_global_load_lds(
        (const __attribute__((address_space(1))) unsigned int*)g,
        (__attribute__((address_space(3))) unsigned int*)l, 16, 0, 0);
}

// ---------------- degree / norm / CSR build ----------------
__global__ void k_zero(int* __restrict__ p, int n) {
    int i = blockIdx.x * 256 + threadIdx.x;
    if (i < n) p[i] = 0;
}

// XCD-partitioned: group g = blockIdx&7 handles dst in [g*n/8,(g+1)*n/8)
__global__ void k_deg_count(const int* __restrict__ ei, int* __restrict__ ecnt,
                            int E, int n) {
    int g = blockIdx.x & (NGRP - 1);
    int bi = blockIdx.x >> 3;
    int nbg = gridDim.x >> 3;
    int lo = (int)((long)g * n / NGRP), hi = (int)((long)(g + 1) * n / NGRP);
    for (int e = bi * 256 + threadIdx.x; e < E; e += nbg * 256) {
        int d = ei[E + e];
        if (d >= lo && d < hi) atomicAdd(&ecnt[d], 1);
    }
}

// ---------------- 3-phase device-wide exclusive scan (+ dinv fused) ----------------
__global__ __launch_bounds__(1024) void k_scanA(const int* __restrict__ ecnt,
                                                int* __restrict__ rowptr,
                                                int* __restrict__ bsum,
                                                float* __restrict__ dinv, int n) {
    __shared__ int tmp[1024];
    int t = threadIdx.x;
    int gid = blockIdx.x * 1024 + t;
    int v = (gid < n) ? ecnt[gid] : 0;
    if (gid < n) dinv[gid] = rsqrtf((float)(v + 1));  // +1 self-loop
    tmp[t] = v;
    __syncthreads();
    for (int off = 1; off < 1024; off <<= 1) {
        int u = (t >= off) ? tmp[t - off] : 0;
        __syncthreads();
        tmp[t] += u;
        __syncthreads();
    }
    if (gid < n) rowptr[gid] = tmp[t] - v;
    if (t == 1023) bsum[blockIdx.x] = tmp[1023];
}

__global__ void k_scanB(const int* __restrict__ bsum, int* __restrict__ boffs, int nb) {
    int t = threadIdx.x;
    int v = (t < nb) ? bsum[t] : 0;
    int inc = v;
#pragma unroll
    for (int off = 1; off < 64; off <<= 1) {
        int u = __shfl_up(inc, off);
        if (t >= off) inc += u;
    }
    if (t < nb) boffs[t] = inc - v;
    if (t == nb - 1) boffs[nb] = inc;
}

__global__ __launch_bounds__(1024) void k_scanC(int* __restrict__ rowptr,
                                                int* __restrict__ cur,
                                                const int* __restrict__ boffs,
                                                int n, int nb) {
    int gid = blockIdx.x * 1024 + threadIdx.x;
    if (gid < n) {
        int v = rowptr[gid] + boffs[blockIdx.x];
        rowptr[gid] = v;
        cur[gid] = v;
    } else if (gid == n) {
        rowptr[n] = boffs[nb];
    }
}

// XCD-partitioned CSR fill
__global__ void k_fill(const int* __restrict__ ei, int* __restrict__ cur,
                       int* __restrict__ csr, int E, int n) {
    int g = blockIdx.x & (NGRP - 1);
    int bi = blockIdx.x >> 3;
    int nbg = gridDim.x >> 3;
    int lo = (int)((long)g * n / NGRP), hi = (int)((long)(g + 1) * n / NGRP);
    for (int e = bi * 256 + threadIdx.x; e < E; e += nbg * 256) {
        int d = ei[E + e];
        if (d >= lo && d < hi) {
            int pos = atomicAdd(&cur[d], 1);
            csr[pos] = ei[e];  // src
        }
    }
}

// ---------------- weight converts: W1 -> Btg[128 cols][512 k]; W2 -> Wt2[64 cols][128 k] ----
__global__ void k_wcvt(const float* __restrict__ W1, const float* __restrict__ W2,
                       unsigned short* __restrict__ Btg, unsigned short* __restrict__ Wt2) {
    int b = blockIdx.x;
    if (b < 256) {
        int id = b * 256 + threadIdx.x;   // 65536
        int kk = id >> 7, c = id & 127;
        float v = (kk < F_IN) ? W1[kk * F_HID + c] : 0.f;
        Btg[c * 512 + kk] = pack_bf16(v);
    } else {
        int id = (b - 256) * 256 + threadIdx.x;  // 8192 (32 blocks)
        int c = id >> 7, kk = id & 127;          // Wt2[col][k], cols 47..63 zero
        float v = (c < F_OUT) ? W2[kk * F_OUT + c] : 0.f;
        Wt2[c * 128 + kk] = pack_bf16(v);
    }
}

// ---------------- GEMM1 (bf16 MFMA, async pipeline): hs16 = bf16((x @ W1) * dinv) ----------
// BM=32, BK=64, 4 waves, double-buffered LDS (40 KB -> 4 blocks/CU), ONE barrier/chunk.
// B staged via global_load_lds with pre-swizzled per-lane SOURCE (linear LDS dest);
// ds_read side applies the same XOR involution (cg ^= r&7 at 16B-group level).
#define BM 32
#define BK 64
__global__ __launch_bounds__(256, 4) void k_gemm1_mfma(const float* __restrict__ x,
                                                       const unsigned short* __restrict__ Btg,
                                                       const float* __restrict__ dinv,
                                                       unsigned short* __restrict__ hs16, int n) {
    __shared__ unsigned short As[2][BM * BK];     // 2 x 4 KB, XOR-swizzled
    __shared__ unsigned short Bs[2][F_HID * BK];  // 2 x 16 KB, XOR-swizzled content
    int t = threadIdx.x;
    int row0 = blockIdx.x * BM;
    int w = t >> 6, l = t & 63;

    int ar = t >> 3, acg = t & 7;
    int agrow = row0 + ar;
    int abyte = ar * 128 + ((acg * 16) ^ ((ar & 7) << 4));

    f32x4 acc[2][2] = {};

#define LOAD_A(c, f0, f1)                                              \
    {                                                                  \
        int kbase = (c) * BK + acg * 8;                                \
        f0 = make_float4(0.f, 0.f, 0.f, 0.f);                          \
        f1 = make_float4(0.f, 0.f, 0.f, 0.f);                          \
        if (agrow < n) {                                               \
            const float* p = x + (long)agrow * F_IN + kbase;           \
            if (kbase + 4 <= F_IN) f0 = *(const float4*)p;             \
            if (kbase + 8 <= F_IN) f1 = *(const float4*)(p + 4);       \
        }                                                              \
    }
    // B stage: lane slot u = t + uu*256 -> LDS linear byte u*16 (= r*128+cg*16),
    // source element group cg ^ (r&7) so that swizzled READ finds global[r][g].
#define STAGE_B(c, bsel)                                                         \
    {                                                                            \
        _Pragma("unroll")                                                        \
        for (int uu = 0; uu < 4; ++uu) {                                         \
            int u = t + uu * 256;                                                \
            int r = u >> 3, cg = u & 7;                                          \
            const unsigned short* gp =                                           \
                Btg + r * 512 + (c) * BK + ((cg ^ (r & 7)) * 8);                 \
            void* lp = (char*)&Bs[bsel][0] + (w * 1024 + uu * 4096);             \
            gload_lds16(gp, lp);                                                 \
        }                                                                        \
    }
#define WRITE_A(bsel, f0, f1)                                                    \
    {                                                                            \
        uint4 pk;                                                                \
        pk.x = pack_bf16x2(f0.x, f0.y);                                          \
        pk.y = pack_bf16x2(f0.z, f0.w);                                          \
        pk.z = pack_bf16x2(f1.x, f1.y);                                          \
        pk.w = pack_bf16x2(f1.z, f1.w);                                          \
        *(uint4*)((char*)&As[bsel][0] + abyte) = pk;                             \
    }

    // prologue: stage chunk 0 into buffer 0
    {
        float4 a0, a1;
        STAGE_B(0, 0);
        LOAD_A(0, a0, a1);
        WRITE_A(0, a0, a1);
    }
    __syncthreads();  // drains vmcnt -> B(0) landed, A(0) written

    int buf = 0;
    for (int c = 0; c < 8; ++c) {
        float4 na0, na1;
        if (c < 7) {
            STAGE_B(c + 1, buf ^ 1);   // async direct-to-LDS
            LOAD_A(c + 1, na0, na1);   // regs in flight across MFMA phase
        }

        int lr = l & 15;
        int lkb = (l >> 4) * 16;
        short8 af[2][2], bf[2][2];
#pragma unroll
        for (int mi = 0; mi < 2; ++mi)
#pragma unroll
            for (int ks = 0; ks < 2; ++ks) {
                int r = mi * 16 + lr;
                int byte = r * 128 + (((ks * 64) + lkb) ^ ((r & 7) << 4));
                af[mi][ks] = *(short8*)((char*)&As[buf][0] + byte);
            }
#pragma unroll
        for (int ni = 0; ni < 2; ++ni)
#pragma unroll
            for (int ks = 0; ks < 2; ++ks) {
                int r = w * 32 + ni * 16 + lr;
                int byte = r * 128 + (((ks * 64) + lkb) ^ ((r & 7) << 4));
                bf[ni][ks] = *(short8*)((char*)&Bs[buf][0] + byte);
            }
#pragma unroll
        for (int mi = 0; mi < 2; ++mi)
#pragma unroll
            for (int ni = 0; ni < 2; ++ni)
#pragma unroll
                for (int ks = 0; ks < 2; ++ks)
                    acc[mi][ni] = __builtin_amdgcn_mfma_f32_16x16x32_bf16(
                        af[mi][ks], bf[ni][ks], acc[mi][ni], 0, 0, 0);

        if (c < 7) WRITE_A(buf ^ 1, na0, na1);  // implicit vmcnt wait on na regs
        __syncthreads();                        // drain -> B(c+1) landed; buf consumed
        buf ^= 1;
    }

#pragma unroll
    for (int mi = 0; mi < 2; ++mi) {
        int rb = row0 + mi * 16 + (l >> 4) * 4;
        float dv[4];
#pragma unroll
        for (int reg = 0; reg < 4; ++reg)
            dv[reg] = (rb + reg < n) ? dinv[rb + reg] : 0.f;
#pragma unroll
        for (int ni = 0; ni < 2; ++ni) {
            int col = w * 32 + ni * 16 + (l & 15);
#pragma unroll
            for (int reg = 0; reg < 4; ++reg) {
                int row = rb + reg;
                if (row < n) hs16[(long)row * F_HID + col] = pack_bf16(acc[mi][ni][reg] * dv[reg]);
            }
        }
    }
#undef LOAD_A
#undef STAGE_B
#undef WRITE_A
}

// ---------------- gather layer 1: h1 = bf16(relu(dinv*(hs16[self]+sum hs16[src]) + b1)) ----
__global__ __launch_bounds__(256) void k_gather1(const unsigned short* __restrict__ hs16,
                                                 const int* __restrict__ rowptr,
                                                 const int* __restrict__ csr,
                                                 const float* __restrict__ dinv,
                                                 const float* __restrict__ b1,
                                                 unsigned short* __restrict__ h1, int n) {
    int tid = blockIdx.x * 256 + threadIdx.x;
    int node = tid >> 5;
    if (node >= n) return;
    int q = tid & 31;
    float4 v;
    {
        uint2 u = *(const uint2*)(hs16 + (long)node * F_HID + q * 4);  // self
        v.x = __uint_as_float(u.x << 16);
        v.y = __uint_as_float(u.x & 0xFFFF0000u);
        v.z = __uint_as_float(u.y << 16);
        v.w = __uint_as_float(u.y & 0xFFFF0000u);
    }
    int lo = rowptr[node], hi = rowptr[node + 1];
    for (int e = lo; e < hi; ++e) {
        int s = csr[e];
        uint2 u = *(const uint2*)(hs16 + (long)s * F_HID + q * 4);
        v.x += __uint_as_float(u.x << 16);
        v.y += __uint_as_float(u.x & 0xFFFF0000u);
        v.z += __uint_as_float(u.y << 16);
        v.w += __uint_as_float(u.y & 0xFFFF0000u);
    }
    float dv = dinv[node];
    float4 bb = *(const float4*)&b1[q * 4];
    float r0 = fmaxf(dv * v.x + bb.x, 0.f);
    float r1 = fmaxf(dv * v.y + bb.y, 0.f);
    float r2 = fmaxf(dv * v.z + bb.z, 0.f);
    float r3 = fmaxf(dv * v.w + bb.w, 0.f);
    uint2 o;
    o.x = pack_bf16x2(r0, r1);
    o.y = pack_bf16x2(r2, r3);
    *(uint2*)(h1 + (long)node * F_HID + q * 4) = o;
}

// ---------------- GEMM2 (bf16 MFMA, no LDS): hs2 = bf16((h1 @ W2) * dinv), 64-col pad ----
__global__ __launch_bounds__(256, 4) void k_gemm2_mfma(const unsigned short* __restrict__ h1,
                                                       const unsigned short* __restrict__ Wt2,
                                                       const float* __restrict__ dinv,
                                                       unsigned short* __restrict__ hs2, int n) {
    int t = threadIdx.x, w = t >> 6, l = t & 63;
    int row0 = blockIdx.x * 32 + (w & 1) * 16;
    int col0 = (w >> 1) * 32;
    int lr = l & 15, lk = (l >> 4) * 8;

    short8 bf[2][4];
#pragma unroll
    for (int nf = 0; nf < 2; ++nf)
#pragma unroll
        for (int ks = 0; ks < 4; ++ks)
            bf[nf][ks] = *(const short8*)(Wt2 + (col0 + nf * 16 + lr) * 128 + ks * 32 + lk);

    int arow = row0 + lr;
    const short8 z8 = {};
    f32x4 acc[2] = {};
#pragma unroll
    for (int ks = 0; ks < 4; ++ks) {
        short8 af = (arow < n) ? *(const short8*)(h1 + (long)arow * F_HID + ks * 32 + lk) : z8;
#pragma unroll
        for (int nf = 0; nf < 2; ++nf)
            acc[nf] = __builtin_amdgcn_mfma_f32_16x16x32_bf16(af, bf[nf][ks], acc[nf], 0, 0, 0);
    }

    int rb = row0 + (l >> 4) * 4;
#pragma unroll
    for (int nf = 0; nf < 2; ++nf) {
        int col = col0 + nf * 16 + lr;
#pragma unroll
        for (int reg = 0; reg < 4; ++reg) {
            int row = rb + reg;
            if (row < n) hs2[(long)row * 64 + col] = pack_bf16(acc[nf][reg] * dinv[row]);
        }
    }
}

// ---------------- gather layer 2 + bias + log_softmax ----------------
__global__ __launch_bounds__(256) void k_out(const unsigned short* __restrict__ hs2,
                                             const int* __restrict__ rowptr,
                                             const int* __restrict__ csr,
                                             const float* __restrict__ dinv,
                                             const float* __restrict__ b2,
                                             float* __restrict__ out, int n) {
    int tid = blockIdx.x * 256 + threadIdx.x;
    int node = tid >> 5;
    if (node >= n) return;
    int q = tid & 31;
    int c0 = 2 * q, c1 = 2 * q + 1;
    float v0, v1;
    {
        unsigned u = *(const unsigned*)(hs2 + (long)node * 64 + c0);  // self
        v0 = __uint_as_float(u << 16);
        v1 = __uint_as_float(u & 0xFFFF0000u);
    }
    int lo = rowptr[node], hi = rowptr[node + 1];
    for (int e = lo; e < hi; ++e) {
        int s = csr[e];
        unsigned u = *(const unsigned*)(hs2 + (long)s * 64 + c0);
        v0 += __uint_as_float(u << 16);
        v1 += __uint_as_float(u & 0xFFFF0000u);
    }
    float dv = dinv[node];
    float z0 = (c0 < F_OUT) ? v0 * dv + b2[c0] : -INFINITY;
    float z1 = (c1 < F_OUT) ? v1 * dv + b2[c1] : -INFINITY;
    float m = fmaxf(z0, z1);
#pragma unroll
    for (int o = 16; o; o >>= 1) m = fmaxf(m, __shfl_xor(m, o));
    float sum = ((c0 < F_OUT) ? __expf(z0 - m) : 0.f) + ((c1 < F_OUT) ? __expf(z1 - m) : 0.f);
#pragma unroll
    for (int o = 16; o; o >>= 1) sum += __shfl_xor(sum, o);
    float ls = logf(sum) + m;
    if (c0 < F_OUT) out[(long)node * F_OUT + c0] = z0 - ls;
    if (c1 < F_OUT) out[(long)node * F_OUT + c1] = z1 - ls;
}

extern "C" void kernel_launch(void* const* d_in, const int* in_sizes, int n_in,
                              void* d_out, int out_size, void* d_ws, size_t ws_size,
                              hipStream_t stream) {
    const float* x  = (const float*)d_in[0];
    const float* W1 = (const float*)d_in[1];
    const float* b1 = (const float*)d_in[2];
    const float* W2 = (const float*)d_in[3];
    const float* b2 = (const float*)d_in[4];
    const int*   ei = (const int*)d_in[5];

    int n = in_sizes[0] / F_IN;      // 50000
    int E = in_sizes[5] / 2;         // 800000
    float* out = (float*)d_out;

    // workspace layout
    char* ws = (char*)d_ws;
    float* dinv   = (float*)(ws + 0);          // 200 KB
    int*   ecnt   = (int*)  (ws + 200704);
    int*   rowptr = (int*)  (ws + 401408);     // n+1 ints
    int*   cur    = (int*)  (ws + 602112);     // dead after k_fill; Btg aliases it
    unsigned short* Btg = (unsigned short*)(ws + 602112);  // 128 KB (ends 733184)
    int*   bsum   = (int*)  (ws + 733184);
    int*   boffs  = (int*)  (ws + 737280);
    unsigned short* Wt2 = (unsigned short*)(ws + 741376);  // 16 KB (ends 757760)
    int*   csr    = (int*)  (ws + 802816);     // 3.2 MB
    unsigned short* hs16  = (unsigned short*)(ws + 4003840);   // 12.8 MB
    unsigned short* hs2   = (unsigned short*)(ws + 16804864);  // 6.4 MB
    unsigned short* h1    = (unsigned short*)(ws + 29603840);  // 12.8 MB

    int nb = (n + 255) / 256;
    int sb = (n + 1023) / 1024;
    k_zero<<<nb, 256, 0, stream>>>(ecnt, n);
    k_deg_count<<<1024, 256, 0, stream>>>(ei, ecnt, E, n);
    k_scanA<<<sb, 1024, 0, stream>>>(ecnt, rowptr, bsum, dinv, n);
    k_scanB<<<1, 64, 0, stream>>>(bsum, boffs, sb);
    k_scanC<<<sb, 1024, 0, stream>>>(rowptr, cur, boffs, n, sb);
    k_fill<<<1024, 256, 0, stream>>>(ei, cur, csr, E, n);
    k_wcvt<<<288, 256, 0, stream>>>(W1, W2, Btg, Wt2);

    k_gemm1_mfma<<<(n + BM - 1) / BM, 256, 0, stream>>>(x, Btg, dinv, hs16, n);
    k_gather1<<<(n * 32 + 255) / 256, 256, 0, stream>>>(hs16, rowptr, csr, dinv, b1, h1, n);
    k_gemm2_mfma<<<(n + 31) / 32, 256, 0, stream>>>(h1, Wt2, dinv, hs2, n);
    k_out<<<(n * 32 + 255) / 256, 256, 0, stream>>>(hs2, rowptr, csr, dinv, b2, out, n);
}